// Round 1
// baseline (169.133 us; speedup 1.0000x reference)
//
#include <hip/hip_runtime.h>
#include <math.h>

// Problem constants (from setup_inputs): B=4, H=W=64, M=8, K=64
#define HW    4096      // H*W
#define KK    64
#define TT    64        // M*M
#define WPB   4         // waves per block
#define BLK   (WPB*64)

__device__ __forceinline__ float softplusf(float x) {
    // jax.nn.softplus: max(x,0) + log1p(exp(-|x|))
    return fmaxf(x, 0.0f) + log1pf(expf(-fabsf(x)));
}

__global__ __launch_bounds__(BLK) void assign_loss_kernel(
    const float* __restrict__ ps,      // [B,HW,K]
    const float* __restrict__ po,      // [B,HW,K,2]
    const int*   __restrict__ tgt,     // [B, 512, 512]
    float* __restrict__ pobj,          // [nblocks]
    float* __restrict__ ploc,          // [nblocks]
    int*   __restrict__ pnp,           // [nblocks]
    int total_waves)
{
    const int lane = threadIdx.x & 63;
    const int wib  = threadIdx.x >> 6;                 // wave index in block
    const int wid  = blockIdx.x * WPB + wib;           // global wave = (b,n)

    float focal = 0.0f, locl = 0.0f;
    int npos = 0;

    if (wid < total_waves) {
        const int b = wid / HW;
        const int n = wid & (HW - 1);
        const int h = n >> 6;           // n / W
        const int w = n & 63;           // n % W

        // per-lane prediction slot data
        const int base = wid * KK + lane;
        const float s   = ps[base];
        const float po0 = po[base * 2 + 0];
        const float po1 = po[base * 2 + 1];

        // per-lane target cell (lane = i*8 + j)
        const int ti = lane >> 3, tj = lane & 7;
        const int tv = tgt[((b * 512) + h * 8 + ti) * 512 + (w * 8 + tj)] > 0;
        const unsigned long long mask = __ballot(tv);

        const float sig  = 1.0f / (1.0f + expf(-s));
        // cls_cost^0.2 for block_target==1: |sig - 1|^0.2 = (1-sig)^0.2 (loop-invariant)
        const float clsc = powf(1.0f - sig, 0.2f);

        npos = __popcll(mask);

        bool  assigned = false;
        float tby = 0.0f, tbx = 0.0f;

        unsigned long long m = mask;
        for (int it = 0; it < npos; ++it) {
            const int t = __ffsll((long long)m) - 1;
            m &= (m - 1);
            const float by = (float)(t >> 3) * 0.125f - 0.4375f; // ((i-3.5)/8)
            const float bx = (float)(t & 7)  * 0.125f - 0.4375f;

            float cost;
            if (assigned) {
                cost = 1e9f;                                    // BIG
            } else {
                const float loc = fabsf(po0 - by) + fabsf(po1 - bx);
                cost = powf(loc, 0.8f) * clsc;
            }

            // argmin over lanes, first-index tie-break:
            // key = (float bits of nonneg cost) << 6 | lane, min-reduce
            unsigned long long key =
                ((unsigned long long)__float_as_uint(cost) << 6) |
                (unsigned long long)lane;
            for (int o = 32; o; o >>= 1) {
                unsigned long long other = __shfl_xor(key, o, 64);
                key = (other < key) ? other : key;
            }
            const int winner = (int)(key & 63ull);
            if (lane == winner) {
                assigned = true;
                tby = by;
                tbx = bx;
            }
        }

        // focal loss for this slot (t = assigned ? 1 : 0)
        // ce: t=1 -> softplus(-s); t=0 -> softplus(s)
        const float ce  = assigned ? softplusf(-s) : softplusf(s);
        const float p_t = assigned ? sig : (1.0f - sig);
        const float om  = 1.0f - p_t;
        focal = ce * om * om * (assigned ? 0.6f : 0.4f);
        locl  = assigned ? (fabsf(po0 - tby) + fabsf(po1 - tbx)) : 0.0f;
    }

    // wave-level sum
    for (int o = 32; o; o >>= 1) {
        focal += __shfl_xor(focal, o, 64);
        locl  += __shfl_xor(locl,  o, 64);
    }

    // block-level combine (4 waves)
    __shared__ float sobj[WPB], sloc[WPB];
    __shared__ int   snp[WPB];
    if (lane == 0) { sobj[wib] = focal; sloc[wib] = locl; snp[wib] = npos; }
    __syncthreads();
    if (threadIdx.x == 0) {
        float o = 0.0f, l = 0.0f; int np = 0;
        #pragma unroll
        for (int q = 0; q < WPB; ++q) { o += sobj[q]; l += sloc[q]; np += snp[q]; }
        pobj[blockIdx.x] = o;
        ploc[blockIdx.x] = l;
        pnp [blockIdx.x] = np;
    }
}

__global__ __launch_bounds__(256) void finalize_kernel(
    const float* __restrict__ pobj,
    const float* __restrict__ ploc,
    const int*   __restrict__ pnp,
    int nb, float* __restrict__ out)
{
    __shared__ double so[256], sl[256];
    __shared__ long long sn[256];
    double o = 0.0, l = 0.0;
    long long np = 0;
    for (int i = threadIdx.x; i < nb; i += 256) {
        o  += (double)pobj[i];
        l  += (double)ploc[i];
        np += (long long)pnp[i];
    }
    so[threadIdx.x] = o; sl[threadIdx.x] = l; sn[threadIdx.x] = np;
    __syncthreads();
    for (int st = 128; st; st >>= 1) {
        if (threadIdx.x < st) {
            so[threadIdx.x] += so[threadIdx.x + st];
            sl[threadIdx.x] += sl[threadIdx.x + st];
            sn[threadIdx.x] += sn[threadIdx.x + st];
        }
        __syncthreads();
    }
    if (threadIdx.x == 0) {
        long long npos = sn[0] > 1 ? sn[0] : 1;
        double norm = (double)npos;
        out[0] = (float)((so[0] + 10.0 * sl[0]) / norm);
    }
}

extern "C" void kernel_launch(void* const* d_in, const int* in_sizes, int n_in,
                              void* d_out, int out_size, void* d_ws, size_t ws_size,
                              hipStream_t stream) {
    const float* ps  = (const float*)d_in[0];   // pred_scores  [B,HW,K] f32
    const float* po  = (const float*)d_in[1];   // pred_offsets [B,HW,K,2] f32
    const int*   tgt = (const int*)d_in[2];     // target [B,512,512] i32

    const int B = in_sizes[0] / (HW * KK);      // = 4
    const int total_waves = B * HW;             // 16384
    const int nblocks = (total_waves + WPB - 1) / WPB;  // 4096

    float* pobj = (float*)d_ws;
    float* ploc = pobj + nblocks;
    int*   pnp  = (int*)(ploc + nblocks);

    assign_loss_kernel<<<nblocks, BLK, 0, stream>>>(
        ps, po, tgt, pobj, ploc, pnp, total_waves);
    finalize_kernel<<<1, 256, 0, stream>>>(
        pobj, ploc, pnp, nblocks, (float*)d_out);
}

// Round 2
// 54.811 us; speedup vs baseline: 3.0858x; 3.0858x over previous
//
#include <hip/hip_runtime.h>
#include <math.h>

// Problem constants (from setup_inputs): B=4, H=W=64, M=8, K=64
#define HW    4096      // H*W
#define KK    64
#define WPB   4         // waves per block
#define BLK   (WPB*64)

__device__ __forceinline__ float softplusf(float x) {
    // jax.nn.softplus: max(x,0) + log1p(exp(-|x|))
    return fmaxf(x, 0.0f) + log1pf(expf(-fabsf(x)));
}

__global__ __launch_bounds__(BLK) void assign_loss_kernel(
    const float*  __restrict__ ps,     // [B,HW,K]
    const float2* __restrict__ po,     // [B,HW,K] of float2
    const int*    __restrict__ tgt,    // [B, 512, 512]
    float* __restrict__ pobj,          // [nblocks]
    float* __restrict__ ploc,          // [nblocks]
    int*   __restrict__ pnp,           // [nblocks]
    int total_waves)
{
    const int lane = threadIdx.x & 63;
    const int wib  = threadIdx.x >> 6;                 // wave index in block
    const int wid  = blockIdx.x * WPB + wib;           // global wave = (b,n)

    float focal = 0.0f, locl = 0.0f;
    int npos = 0;

    if (wid < total_waves) {
        const int b = wid / HW;
        const int n = wid & (HW - 1);
        const int h = n >> 6;           // n / W
        const int w = n & 63;           // n % W

        // per-lane prediction slot data (coalesced)
        const int base = wid * KK + lane;
        const float  s  = ps[base];
        const float2 pv = po[base];
        const float po0 = pv.x, po1 = pv.y;

        // per-lane target cell (lane = i*8 + j)
        const int ti = lane >> 3, tj = lane & 7;
        const int tv = tgt[((b * 512) + h * 8 + ti) * 512 + (w * 8 + tj)] > 0;
        const unsigned long long mask = __ballot(tv);

        const float sig = 1.0f / (1.0f + expf(-s));
        // order-equivalent class factor: ((1-sig)^0.2)^1.25 = (1-sig)^0.25
        const float cl  = powf(1.0f - sig, 0.25f);

        npos = __popcll(mask);

        bool  assigned = false;
        float tby = 0.0f, tbx = 0.0f;

        unsigned long long m = mask;
        for (int it = 0; it < npos; ++it) {
            const int t = __ffsll((unsigned long long)m) - 1;
            m &= (m - 1);
            const float by = (float)(t >> 3) * 0.125f - 0.4375f; // (i-3.5)/8
            const float bx = (float)(t & 7)  * 0.125f - 0.4375f;

            // order-equivalent cost: (loc^0.8 * (1-sig)^0.2)^1.25 = loc * cl
            const float loc = fabsf(po0 - by) + fabsf(po1 - bx);
            const float c   = assigned ? 1e30f : (loc * cl);

            // wave min-reduce (butterfly), then first-lane tie-break
            float mn = c;
            #pragma unroll
            for (int o = 1; o < 64; o <<= 1)
                mn = fminf(mn, __shfl_xor(mn, o, 64));
            const unsigned long long eq = __ballot(c == mn);
            const int winner = __ffsll(eq) - 1;
            if (lane == winner) {
                assigned = true;
                tby = by;
                tbx = bx;
            }
        }

        // focal loss for this slot (t = assigned ? 1 : 0)
        const float ce  = assigned ? softplusf(-s) : softplusf(s);
        const float p_t = assigned ? sig : (1.0f - sig);
        const float om  = 1.0f - p_t;
        focal = ce * om * om * (assigned ? 0.6f : 0.4f);
        locl  = assigned ? (fabsf(po0 - tby) + fabsf(po1 - tbx)) : 0.0f;
    }

    // wave-level sum
    #pragma unroll
    for (int o = 32; o; o >>= 1) {
        focal += __shfl_xor(focal, o, 64);
        locl  += __shfl_xor(locl,  o, 64);
    }

    // block-level combine (4 waves)
    __shared__ float sobj[WPB], sloc[WPB];
    __shared__ int   snp[WPB];
    if (lane == 0) { sobj[wib] = focal; sloc[wib] = locl; snp[wib] = npos; }
    __syncthreads();
    if (threadIdx.x == 0) {
        float o = 0.0f, l = 0.0f; int np = 0;
        #pragma unroll
        for (int q = 0; q < WPB; ++q) { o += sobj[q]; l += sloc[q]; np += snp[q]; }
        pobj[blockIdx.x] = o;
        ploc[blockIdx.x] = l;
        pnp [blockIdx.x] = np;
    }
}

__global__ __launch_bounds__(256) void finalize_kernel(
    const float* __restrict__ pobj,
    const float* __restrict__ ploc,
    const int*   __restrict__ pnp,
    int nb, float* __restrict__ out)
{
    __shared__ double so[256], sl[256];
    __shared__ long long sn[256];
    double o = 0.0, l = 0.0;
    long long np = 0;
    for (int i = threadIdx.x; i < nb; i += 256) {
        o  += (double)pobj[i];
        l  += (double)ploc[i];
        np += (long long)pnp[i];
    }
    so[threadIdx.x] = o; sl[threadIdx.x] = l; sn[threadIdx.x] = np;
    __syncthreads();
    for (int st = 128; st; st >>= 1) {
        if (threadIdx.x < st) {
            so[threadIdx.x] += so[threadIdx.x + st];
            sl[threadIdx.x] += sl[threadIdx.x + st];
            sn[threadIdx.x] += sn[threadIdx.x + st];
        }
        __syncthreads();
    }
    if (threadIdx.x == 0) {
        long long npos = sn[0] > 1 ? sn[0] : 1;
        double norm = (double)npos;
        out[0] = (float)((so[0] + 10.0 * sl[0]) / norm);
    }
}

extern "C" void kernel_launch(void* const* d_in, const int* in_sizes, int n_in,
                              void* d_out, int out_size, void* d_ws, size_t ws_size,
                              hipStream_t stream) {
    const float*  ps  = (const float*)d_in[0];   // pred_scores  [B,HW,K] f32
    const float2* po  = (const float2*)d_in[1];  // pred_offsets [B,HW,K,2] f32
    const int*    tgt = (const int*)d_in[2];     // target [B,512,512] i32

    const int B = in_sizes[0] / (HW * KK);       // = 4
    const int total_waves = B * HW;              // 16384
    const int nblocks = (total_waves + WPB - 1) / WPB;  // 4096

    float* pobj = (float*)d_ws;
    float* ploc = pobj + nblocks;
    int*   pnp  = (int*)(ploc + nblocks);

    assign_loss_kernel<<<nblocks, BLK, 0, stream>>>(
        ps, po, tgt, pobj, ploc, pnp, total_waves);
    finalize_kernel<<<1, 256, 0, stream>>>(
        pobj, ploc, pnp, nblocks, (float*)d_out);
}

// Round 3
// 44.283 us; speedup vs baseline: 3.8193x; 1.2377x over previous
//
#include <hip/hip_runtime.h>
#include <math.h>

// Problem constants (from setup_inputs): B=4, H=W=64, M=8, K=64
#define HW    4096      // H*W
#define KK    64
#define WPB   4         // waves per block
#define BLK   (WPB*64)

__device__ __forceinline__ float softplusf(float x) {
    // jax.nn.softplus: max(x,0) + log1p(exp(-|x|))
    return fmaxf(x, 0.0f) + log1pf(expf(-fabsf(x)));
}

// Full-wave (64-lane) min of a uint key via DPP (VALU pipe, no LDS).
// Result broadcast to all lanes via readlane from lane 63.
__device__ __forceinline__ unsigned wave_min_u32(unsigned x) {
    unsigned y;
    #define DPPMIN(ctrl)                                                     \
        y = (unsigned)__builtin_amdgcn_update_dpp((int)x, (int)x, ctrl,      \
                                                  0xf, 0xf, false);          \
        x = (y < x) ? y : x;
    DPPMIN(0x111)   // row_shr:1
    DPPMIN(0x112)   // row_shr:2
    DPPMIN(0x114)   // row_shr:4
    DPPMIN(0x118)   // row_shr:8  -> lane 15 of each row16 has row min
    DPPMIN(0x142)   // row_bcast:15 -> lane 31 = min(r0,r1), lane 63 = min(r2,r3)
    DPPMIN(0x143)   // row_bcast:31 -> lane 63 = full min
    #undef DPPMIN
    return (unsigned)__builtin_amdgcn_readlane((int)x, 63);
}

__global__ __launch_bounds__(BLK) void assign_loss_kernel(
    const float*  __restrict__ ps,     // [B,HW,K]
    const float2* __restrict__ po,     // [B,HW,K] of float2
    const int*    __restrict__ tgt,    // [B, 512, 512]
    float* __restrict__ pobj,          // [nblocks]
    float* __restrict__ ploc,          // [nblocks]
    int*   __restrict__ pnp,           // [nblocks]
    int total_waves)
{
    const int lane = threadIdx.x & 63;
    const int wib  = threadIdx.x >> 6;                 // wave index in block
    const int wid  = blockIdx.x * WPB + wib;           // global wave = (b,n)

    float focal = 0.0f, locl = 0.0f;
    int npos = 0;

    if (wid < total_waves) {
        const int b = wid / HW;
        const int n = wid & (HW - 1);
        const int h = n >> 6;           // n / W
        const int w = n & 63;           // n % W

        // per-lane prediction slot data (coalesced)
        const int base = wid * KK + lane;
        const float  s  = ps[base];
        const float2 pv = po[base];
        const float po0 = pv.x, po1 = pv.y;

        // per-lane target cell (lane = i*8 + j)
        const int ti = lane >> 3, tj = lane & 7;
        const int tv = tgt[((b * 512) + h * 8 + ti) * 512 + (w * 8 + tj)] > 0;
        const unsigned long long mask = __ballot(tv);

        const float sig = 1.0f / (1.0f + expf(-s));
        // order-equivalent class factor: ((1-sig)^0.2)^1.25 = (1-sig)^0.25
        const float cl  = powf(1.0f - sig, 0.25f);

        npos = __popcll(mask);

        bool  assigned = false;
        float tby = 0.0f, tbx = 0.0f;

        unsigned long long m = mask;
        while (m) {
            const int t = __ffsll(m) - 1;
            m &= (m - 1);
            const float by = (float)(t >> 3) * 0.125f - 0.4375f; // (i-3.5)/8
            const float bx = (float)(t & 7)  * 0.125f - 0.4375f;

            // order-equivalent cost: (loc^0.8 * cls^0.2)^1.25 = loc * cl
            const float loc = fabsf(po0 - by) + fabsf(po1 - bx);
            const float c   = assigned ? 1e30f : (loc * cl);

            // sortable key: cost >= 0 so float bits preserve order; embed
            // lane in low 6 bits (quantizes cost to 64 ulp; ties -> lowest
            // lane = reference's first-index argmin). Unique per lane.
            const unsigned key = (__float_as_uint(c) & ~63u) | (unsigned)lane;
            const unsigned mn  = wave_min_u32(key);
            if (key == mn) {                    // exactly one lane
                assigned = true;
                tby = by;
                tbx = bx;
            }
        }

        // focal loss for this slot (t = assigned ? 1 : 0)
        const float ce  = assigned ? softplusf(-s) : softplusf(s);
        const float p_t = assigned ? sig : (1.0f - sig);
        const float om  = 1.0f - p_t;
        focal = ce * om * om * (assigned ? 0.6f : 0.4f);
        locl  = assigned ? (fabsf(po0 - tby) + fabsf(po1 - tbx)) : 0.0f;
    }

    // wave-level sum (these 12 shuffles run once, not per-step: keep simple)
    #pragma unroll
    for (int o = 32; o; o >>= 1) {
        focal += __shfl_xor(focal, o, 64);
        locl  += __shfl_xor(locl,  o, 64);
    }

    // block-level combine (4 waves)
    __shared__ float sobj[WPB], sloc[WPB];
    __shared__ int   snp[WPB];
    if (lane == 0) { sobj[wib] = focal; sloc[wib] = locl; snp[wib] = npos; }
    __syncthreads();
    if (threadIdx.x == 0) {
        float o = 0.0f, l = 0.0f; int np = 0;
        #pragma unroll
        for (int q = 0; q < WPB; ++q) { o += sobj[q]; l += sloc[q]; np += snp[q]; }
        pobj[blockIdx.x] = o;
        ploc[blockIdx.x] = l;
        pnp [blockIdx.x] = np;
    }
}

__global__ __launch_bounds__(256) void finalize_kernel(
    const float* __restrict__ pobj,
    const float* __restrict__ ploc,
    const int*   __restrict__ pnp,
    int nb, float* __restrict__ out)
{
    __shared__ double so[256], sl[256];
    __shared__ long long sn[256];
    double o = 0.0, l = 0.0;
    long long np = 0;
    for (int i = threadIdx.x; i < nb; i += 256) {
        o  += (double)pobj[i];
        l  += (double)ploc[i];
        np += (long long)pnp[i];
    }
    so[threadIdx.x] = o; sl[threadIdx.x] = l; sn[threadIdx.x] = np;
    __syncthreads();
    for (int st = 128; st; st >>= 1) {
        if (threadIdx.x < st) {
            so[threadIdx.x] += so[threadIdx.x + st];
            sl[threadIdx.x] += sl[threadIdx.x + st];
            sn[threadIdx.x] += sn[threadIdx.x + st];
        }
        __syncthreads();
    }
    if (threadIdx.x == 0) {
        long long npos = sn[0] > 1 ? sn[0] : 1;
        double norm = (double)npos;
        out[0] = (float)((so[0] + 10.0 * sl[0]) / norm);
    }
}

extern "C" void kernel_launch(void* const* d_in, const int* in_sizes, int n_in,
                              void* d_out, int out_size, void* d_ws, size_t ws_size,
                              hipStream_t stream) {
    const float*  ps  = (const float*)d_in[0];   // pred_scores  [B,HW,K] f32
    const float2* po  = (const float2*)d_in[1];  // pred_offsets [B,HW,K,2] f32
    const int*    tgt = (const int*)d_in[2];     // target [B,512,512] i32

    const int B = in_sizes[0] / (HW * KK);       // = 4
    const int total_waves = B * HW;              // 16384
    const int nblocks = (total_waves + WPB - 1) / WPB;  // 4096

    float* pobj = (float*)d_ws;
    float* ploc = pobj + nblocks;
    int*   pnp  = (int*)(ploc + nblocks);

    assign_loss_kernel<<<nblocks, BLK, 0, stream>>>(
        ps, po, tgt, pobj, ploc, pnp, total_waves);
    finalize_kernel<<<1, 256, 0, stream>>>(
        pobj, ploc, pnp, nblocks, (float*)d_out);
}

// Round 5
// 39.352 us; speedup vs baseline: 4.2980x; 1.1253x over previous
//
#include <hip/hip_runtime.h>
#include <math.h>

// Problem constants (from setup_inputs): B=4, H=W=64, M=8, K=64
#define HW    4096      // H*W
#define KK    64
#define WPB   4         // waves per block
#define BLK   (WPB*64)

__device__ __forceinline__ float softplusf(float x) {
    // jax.nn.softplus: max(x,0) + log1p(exp(-|x|))
    return fmaxf(x, 0.0f) + log1pf(expf(-fabsf(x)));
}

// Full-wave (64-lane) min of a uint key via DPP on the VALU pipe.
// Uses __builtin_amdgcn_update_dpp so the COMPILER handles the
// VALU->DPP-read hazard wait states (raw asm DPP chain = stale data).
// bound_ctrl=false + old=x -> invalid-source lanes yield x (no-op for min).
__device__ __forceinline__ unsigned wave_min_u32(unsigned x) {
    unsigned y;
    #define DPPMIN(ctrl)                                                     \
        y = (unsigned)__builtin_amdgcn_update_dpp((int)x, (int)x, ctrl,      \
                                                  0xf, 0xf, false);          \
        x = (y < x) ? y : x;
    DPPMIN(0x111)   // row_shr:1
    DPPMIN(0x112)   // row_shr:2
    DPPMIN(0x114)   // row_shr:4
    DPPMIN(0x118)   // row_shr:8  -> lane 15 of each row16 has row min
    DPPMIN(0x142)   // row_bcast:15
    DPPMIN(0x143)   // row_bcast:31 -> lane 63 = full min
    #undef DPPMIN
    return (unsigned)__builtin_amdgcn_readlane((int)x, 63);
}

__global__ __launch_bounds__(BLK) void assign_loss_kernel(
    const float*  __restrict__ ps,     // [B,HW,K]
    const float2* __restrict__ po,     // [B,HW,K] of float2
    const int*    __restrict__ tgt,    // [B, 512, 512]
    float* __restrict__ pobj,          // [nblocks]
    float* __restrict__ ploc,          // [nblocks]
    int*   __restrict__ pnp,           // [nblocks]
    int total_waves)
{
    const int lane = threadIdx.x & 63;
    const int wib  = threadIdx.x >> 6;                 // wave index in block
    const int wid  = blockIdx.x * WPB + wib;           // global wave = (b,n)

    float focal = 0.0f, locl = 0.0f;
    int npos = 0;

    if (wid < total_waves) {
        const int b = wid / HW;
        const int n = wid & (HW - 1);
        const int h = n >> 6;           // n / W
        const int w = n & 63;           // n % W

        // per-lane prediction slot data (coalesced)
        const int base = wid * KK + lane;
        const float  s  = ps[base];
        const float2 pv = po[base];
        const float po0 = pv.x, po1 = pv.y;

        // per-lane target cell (lane = i*8 + j)
        const int ti = lane >> 3, tj = lane & 7;
        const int tv = tgt[((b * 512) + h * 8 + ti) * 512 + (w * 8 + tj)] > 0;
        const unsigned long long mask = __ballot(tv);
        npos = __popcll(mask);

        const float sig = 1.0f / (1.0f + expf(-s));
        // order-equivalent class factor: ((1-sig)^0.2)^1.25 = (1-sig)^0.25
        float cl = sqrtf(sqrtf(1.0f - sig));
        const float FINF = __uint_as_float(0x7f800000u);

        // greedy assignment: iterate positive targets in raster order.
        // t (and by/bx) are compile-time constants; the branch is wave-
        // uniform scalar (mask is wave-uniform). Assigned slots carry
        // cl=+inf so their cost sorts above every finite cost.
        #pragma unroll 64
        for (int t = 0; t < 64; ++t) {
            if (mask & (1ull << (unsigned long long)t)) {
                const float by = (float)(t >> 3) * 0.125f - 0.4375f; // (i-3.5)/8
                const float bx = (float)(t & 7)  * 0.125f - 0.4375f;
                const float loc = fabsf(po0 - by) + fabsf(po1 - bx);
                const float c   = loc * cl;   // order-equiv: (loc^.8*cls^.2)^1.25
                // sortable unique key: float bits (c>=0) with lane in low 6
                // bits -> ties resolve to lowest lane = first-index argmin
                const unsigned key = (__float_as_uint(c) & ~63u) | (unsigned)lane;
                const unsigned mn  = wave_min_u32(key);
                const bool win = (key == mn);         // exactly one lane
                cl   = win ? FINF : cl;
                locl = win ? loc  : locl;             // each lane wins <= once
            }
        }

        // focal loss for this slot (t = assigned ? 1 : 0)
        const bool assigned = (cl > 1e30f);
        const float ce  = assigned ? softplusf(-s) : softplusf(s);
        const float p_t = assigned ? sig : (1.0f - sig);
        const float om  = 1.0f - p_t;
        focal = ce * om * om * (assigned ? 0.6f : 0.4f);
        if (!assigned) locl = 0.0f;
    }

    // wave-level sum (once per wave)
    #pragma unroll
    for (int o = 32; o; o >>= 1) {
        focal += __shfl_xor(focal, o, 64);
        locl  += __shfl_xor(locl,  o, 64);
    }

    // block-level combine (4 waves)
    __shared__ float sobj[WPB], sloc[WPB];
    __shared__ int   snp[WPB];
    if (lane == 0) { sobj[wib] = focal; sloc[wib] = locl; snp[wib] = npos; }
    __syncthreads();
    if (threadIdx.x == 0) {
        float o = 0.0f, l = 0.0f; int np = 0;
        #pragma unroll
        for (int q = 0; q < WPB; ++q) { o += sobj[q]; l += sloc[q]; np += snp[q]; }
        pobj[blockIdx.x] = o;
        ploc[blockIdx.x] = l;
        pnp [blockIdx.x] = np;
    }
}

__global__ __launch_bounds__(256) void finalize_kernel(
    const float* __restrict__ pobj,
    const float* __restrict__ ploc,
    const int*   __restrict__ pnp,
    int nb, float* __restrict__ out)
{
    __shared__ double so[256], sl[256];
    __shared__ long long sn[256];
    double o = 0.0, l = 0.0;
    long long np = 0;
    for (int i = threadIdx.x; i < nb; i += 256) {
        o  += (double)pobj[i];
        l  += (double)ploc[i];
        np += (long long)pnp[i];
    }
    so[threadIdx.x] = o; sl[threadIdx.x] = l; sn[threadIdx.x] = np;
    __syncthreads();
    for (int st = 128; st; st >>= 1) {
        if (threadIdx.x < st) {
            so[threadIdx.x] += so[threadIdx.x + st];
            sl[threadIdx.x] += sl[threadIdx.x + st];
            sn[threadIdx.x] += sn[threadIdx.x + st];
        }
        __syncthreads();
    }
    if (threadIdx.x == 0) {
        long long npos = sn[0] > 1 ? sn[0] : 1;
        double norm = (double)npos;
        out[0] = (float)((so[0] + 10.0 * sl[0]) / norm);
    }
}

extern "C" void kernel_launch(void* const* d_in, const int* in_sizes, int n_in,
                              void* d_out, int out_size, void* d_ws, size_t ws_size,
                              hipStream_t stream) {
    const float*  ps  = (const float*)d_in[0];   // pred_scores  [B,HW,K] f32
    const float2* po  = (const float2*)d_in[1];  // pred_offsets [B,HW,K,2] f32
    const int*    tgt = (const int*)d_in[2];     // target [B,512,512] i32

    const int B = in_sizes[0] / (HW * KK);       // = 4
    const int total_waves = B * HW;              // 16384
    const int nblocks = (total_waves + WPB - 1) / WPB;  // 4096

    float* pobj = (float*)d_ws;
    float* ploc = pobj + nblocks;
    int*   pnp  = (int*)(ploc + nblocks);

    assign_loss_kernel<<<nblocks, BLK, 0, stream>>>(
        ps, po, tgt, pobj, ploc, pnp, total_waves);
    finalize_kernel<<<1, 256, 0, stream>>>(
        pobj, ploc, pnp, nblocks, (float*)d_out);
}

// Round 6
// 32.640 us; speedup vs baseline: 5.1819x; 1.2057x over previous
//
#include <hip/hip_runtime.h>
#include <math.h>

// Problem constants (from setup_inputs): B=4, H=W=64, M=8, K=64
#define HW    4096      // H*W
#define KK    64
#define WPB   4         // waves per block
#define BLK   (WPB*64)

__device__ __forceinline__ float softplusf(float x) {
    // jax.nn.softplus: max(x,0) + log1p(exp(-|x|))
    return fmaxf(x, 0.0f) + log1pf(expf(-fabsf(x)));
}

// Full-wave (64-lane) min of a uint key: 6 FUSED v_min_u32_dpp ops in one
// asm block. DPP reading a VGPR written by a VALU op needs 2 wait states:
// we provide them with s_nop 1 (scalar pipe - stalls this wave only, does
// not consume VALU issue slots). Leading/trailing s_nop cover the
// boundaries with compiler-emitted code (round-3 lesson: omitting the
// wait states returns stale lane data). Controls identical to the
// builtin version verified in rounds 2/4 (absmax 0.0).
__device__ __forceinline__ unsigned wave_min_u32(unsigned x) {
    asm("s_nop 1\n\t"
        "v_min_u32_dpp %0, %0, %0 row_shr:1  row_mask:0xf bank_mask:0xf\n\t"
        "s_nop 1\n\t"
        "v_min_u32_dpp %0, %0, %0 row_shr:2  row_mask:0xf bank_mask:0xf\n\t"
        "s_nop 1\n\t"
        "v_min_u32_dpp %0, %0, %0 row_shr:4  row_mask:0xf bank_mask:0xf\n\t"
        "s_nop 1\n\t"
        "v_min_u32_dpp %0, %0, %0 row_shr:8  row_mask:0xf bank_mask:0xf\n\t"
        "s_nop 1\n\t"
        "v_min_u32_dpp %0, %0, %0 row_bcast:15 row_mask:0xf bank_mask:0xf\n\t"
        "s_nop 1\n\t"
        "v_min_u32_dpp %0, %0, %0 row_bcast:31 row_mask:0xf bank_mask:0xf\n\t"
        "s_nop 1"
        : "+v"(x));
    return (unsigned)__builtin_amdgcn_readlane((int)x, 63);
}

__global__ __launch_bounds__(BLK) void assign_loss_kernel(
    const float*  __restrict__ ps,     // [B,HW,K]
    const float2* __restrict__ po,     // [B,HW,K] of float2
    const int*    __restrict__ tgt,    // [B, 512, 512]
    float* __restrict__ pobj,          // [nblocks]
    float* __restrict__ ploc,          // [nblocks]
    int*   __restrict__ pnp,           // [nblocks]
    int total_waves)
{
    const int lane = threadIdx.x & 63;
    const int wib  = threadIdx.x >> 6;                 // wave index in block
    const int wid  = blockIdx.x * WPB + wib;           // global wave = (b,n)

    float focal = 0.0f, locl = 0.0f;
    int npos = 0;

    if (wid < total_waves) {
        const int b = wid / HW;
        const int n = wid & (HW - 1);
        const int h = n >> 6;           // n / W
        const int w = n & 63;           // n % W

        // per-lane prediction slot data (coalesced)
        const int base = wid * KK + lane;
        const float  s  = ps[base];
        const float2 pv = po[base];
        const float po0 = pv.x, po1 = pv.y;

        // per-lane target cell (lane = i*8 + j)
        const int ti = lane >> 3, tj = lane & 7;
        const int tv = tgt[((b * 512) + h * 8 + ti) * 512 + (w * 8 + tj)] > 0;
        const unsigned long long mask = __ballot(tv);
        npos = __popcll(mask);

        const float sig = 1.0f / (1.0f + expf(-s));
        // order-equivalent class factor: ((1-sig)^0.2)^1.25 = (1-sig)^0.25
        float cl = sqrtf(sqrtf(1.0f - sig));
        const float FINF = __uint_as_float(0x7f800000u);

        // greedy assignment: iterate positive targets in raster order.
        // t (and by/bx) are compile-time constants; the branch is wave-
        // uniform scalar (mask is wave-uniform). Assigned slots carry
        // cl=+inf so their cost sorts above every finite cost.
        #pragma unroll 64
        for (int t = 0; t < 64; ++t) {
            if (mask & (1ull << (unsigned long long)t)) {
                const float by = (float)(t >> 3) * 0.125f - 0.4375f; // (i-3.5)/8
                const float bx = (float)(t & 7)  * 0.125f - 0.4375f;
                const float loc = fabsf(po0 - by) + fabsf(po1 - bx);
                const float c   = loc * cl;   // order-equiv: (loc^.8*cls^.2)^1.25
                // sortable unique key: float bits (c>=0) with lane in low 6
                // bits -> ties resolve to lowest lane = first-index argmin
                const unsigned key = (__float_as_uint(c) & ~63u) | (unsigned)lane;
                const unsigned mn  = wave_min_u32(key);
                const bool win = (key == mn);         // exactly one lane
                cl   = win ? FINF : cl;
                locl = win ? loc  : locl;             // each lane wins <= once
            }
        }

        // focal loss for this slot (t = assigned ? 1 : 0)
        const bool assigned = (cl > 1e30f);
        const float ce  = assigned ? softplusf(-s) : softplusf(s);
        const float p_t = assigned ? sig : (1.0f - sig);
        const float om  = 1.0f - p_t;
        focal = ce * om * om * (assigned ? 0.6f : 0.4f);
        if (!assigned) locl = 0.0f;
    }

    // wave-level sum (once per wave)
    #pragma unroll
    for (int o = 32; o; o >>= 1) {
        focal += __shfl_xor(focal, o, 64);
        locl  += __shfl_xor(locl,  o, 64);
    }

    // block-level combine (4 waves)
    __shared__ float sobj[WPB], sloc[WPB];
    __shared__ int   snp[WPB];
    if (lane == 0) { sobj[wib] = focal; sloc[wib] = locl; snp[wib] = npos; }
    __syncthreads();
    if (threadIdx.x == 0) {
        float o = 0.0f, l = 0.0f; int np = 0;
        #pragma unroll
        for (int q = 0; q < WPB; ++q) { o += sobj[q]; l += sloc[q]; np += snp[q]; }
        pobj[blockIdx.x] = o;
        ploc[blockIdx.x] = l;
        pnp [blockIdx.x] = np;
    }
}

__global__ __launch_bounds__(256) void finalize_kernel(
    const float* __restrict__ pobj,
    const float* __restrict__ ploc,
    const int*   __restrict__ pnp,
    int nb, float* __restrict__ out)
{
    __shared__ double so[256], sl[256];
    __shared__ long long sn[256];
    double o = 0.0, l = 0.0;
    long long np = 0;
    for (int i = threadIdx.x; i < nb; i += 256) {
        o  += (double)pobj[i];
        l  += (double)ploc[i];
        np += (long long)pnp[i];
    }
    so[threadIdx.x] = o; sl[threadIdx.x] = l; sn[threadIdx.x] = np;
    __syncthreads();
    for (int st = 128; st; st >>= 1) {
        if (threadIdx.x < st) {
            so[threadIdx.x] += so[threadIdx.x + st];
            sl[threadIdx.x] += sl[threadIdx.x + st];
            sn[threadIdx.x] += sn[threadIdx.x + st];
        }
        __syncthreads();
    }
    if (threadIdx.x == 0) {
        long long npos = sn[0] > 1 ? sn[0] : 1;
        double norm = (double)npos;
        out[0] = (float)((so[0] + 10.0 * sl[0]) / norm);
    }
}

extern "C" void kernel_launch(void* const* d_in, const int* in_sizes, int n_in,
                              void* d_out, int out_size, void* d_ws, size_t ws_size,
                              hipStream_t stream) {
    const float*  ps  = (const float*)d_in[0];   // pred_scores  [B,HW,K] f32
    const float2* po  = (const float2*)d_in[1];  // pred_offsets [B,HW,K,2] f32
    const int*    tgt = (const int*)d_in[2];     // target [B,512,512] i32

    const int B = in_sizes[0] / (HW * KK);       // = 4
    const int total_waves = B * HW;              // 16384
    const int nblocks = (total_waves + WPB - 1) / WPB;  // 4096

    float* pobj = (float*)d_ws;
    float* ploc = pobj + nblocks;
    int*   pnp  = (int*)(ploc + nblocks);

    assign_loss_kernel<<<nblocks, BLK, 0, stream>>>(
        ps, po, tgt, pobj, ploc, pnp, total_waves);
    finalize_kernel<<<1, 256, 0, stream>>>(
        pobj, ploc, pnp, nblocks, (float*)d_out);
}